// Round 6
// baseline (95.668 us; speedup 1.0000x reference)
//
#include <hip/hip_runtime.h>

#define BB 2048
#define EMB 128
#define NF 200
#define W_OUT 126
#define EPS 1e-5f

#define SPB 4                     // samples per block (2 pairs)
#define FS 2                      // f-split factor
#define NFB (NF / FS)             // 100 f per block
#define MAIN_BLOCKS (BB / SPB)    // 512 sample-quads

#define SLOTS 6
#define NTASK 42
#define NPAIR 33
#define NGRAM 297
#define NSTAT 324
#define STATS_BLOCKS 342

#define PKD_OFF 3456              // float offset of packed per-f params in ws
#define PKD_STRIDE 32
#define PART_OFF 16384            // float offset of per-fs partial dot products

typedef float f32x2 __attribute__((ext_vector_type(2)));

__device__ __forceinline__ f32x2 fma2(f32x2 a, float s, f32x2 c) {
  return __builtin_elementwise_fma(a, (f32x2){s, s}, c);
}
__device__ __forceinline__ f32x2 fmss(f32x2 a, float s, float sh) {
  return __builtin_elementwise_fma(a, (f32x2){s, s}, (f32x2){sh, sh});
}
__device__ __forceinline__ f32x2 min2(f32x2 a, f32x2 b) {
  return __builtin_elementwise_min(a, b);
}

// ---------------- stats (Gram), x-split x2 ---------------------------------
__device__ __constant__ unsigned char PA_t[NTASK] = {
  0,0,0,1,1,2,
  0,1,2,0,1,2, 3,3,4,
  0,1,2,0,1,2, 5,5,6,
  0,1,2,0,1,2, 7,7,8,
  0,1,2,3,4,5,6,7,8};
__device__ __constant__ unsigned char PB_t[NTASK] = {
  0,1,2,1,2,2,
  3,3,3,4,4,4, 3,4,4,
  5,5,5,6,6,6, 5,6,6,
  7,7,7,8,8,8, 7,8,8,
  9,9,9,9,9,9,9,9,9};

__global__ __launch_bounds__(256, 4) void stats_kernel(
    const int* __restrict__ xb, const float* __restrict__ er,
    const float* __restrict__ ev, float* __restrict__ ws) {
  __shared__ float hs[SLOTS][10][132];
  __shared__ const float* volatile rowp[SLOTS][9];
  __shared__ float red[NSTAT];
  const int tid = threadIdx.x;
  const int base = (blockIdx.x >> 1) * SLOTS;
  const int x0 = (blockIdx.x & 1) * 63;       // x-half of this block

  for (int e = tid; e < SLOTS * EMB; e += 256) hs[e / EMB][9][e & 127] = 1.0f;
  for (int e = tid; e < NSTAT; e += 256) red[e] = 0.f;

  if (tid < SLOTS * 9) {
    int s = tid / 9, r = tid % 9;
    int b = base + s;
    const float* p = nullptr;
    if (b < BB) {
      const int* xr = xb + b * 10;
      if (r == 0)      p = ev + (size_t)xr[1] * EMB;
      else if (r == 1) p = er + (size_t)xr[0] * EMB;
      else if (r == 2) p = ev + (size_t)xr[3] * EMB;
      else {
        int k = (r - 3) >> 1;
        p = ((r - 3) & 1) ? ev + (size_t)xr[5 + 2 * k] * EMB
                          : er + (size_t)xr[4 + 2 * k] * EMB;
      }
    }
    rowp[s][r] = p;
  }
  __syncthreads();
  for (int e = tid; e < SLOTS * 9 * EMB; e += 256) {
    int s = e / (9 * EMB), rem = e % (9 * EMB);
    int r = rem >> 7, col = rem & 127;
    const float* p = (const float*)rowp[s][r];
    hs[s][r][col] = p ? p[col] : 0.f;
  }
  __syncthreads();

  const int slot = tid / NTASK;
  const int task = tid % NTASK;
  if (tid < SLOTS * NTASK) {
    const float* A  = &hs[slot][PA_t[task]][0];
    const float* Bq = &hs[slot][PB_t[task]][0];
    float a00 = 0.f, a01 = 0.f, a02 = 0.f;
    float a10 = 0.f, a11 = 0.f, a12 = 0.f;
    float a20 = 0.f, a21 = 0.f, a22 = 0.f;
    float wa0 = A[x0], wa1 = A[x0 + 1], wb0 = Bq[x0], wb1 = Bq[x0 + 1];
#pragma unroll 3
    for (int x = x0; x < x0 + 63; ++x) {
      float wa2 = A[x + 2], wb2 = Bq[x + 2];
      a00 = fmaf(wa0, wb0, a00); a01 = fmaf(wa0, wb1, a01); a02 = fmaf(wa0, wb2, a02);
      a10 = fmaf(wa1, wb0, a10); a11 = fmaf(wa1, wb1, a11); a12 = fmaf(wa1, wb2, a12);
      a20 = fmaf(wa2, wb0, a20); a21 = fmaf(wa2, wb1, a21); a22 = fmaf(wa2, wb2, a22);
      wa0 = wa1; wa1 = wa2; wb0 = wb1; wb1 = wb2;
    }
    if (task < NPAIR) {
      const int o = task * 9;
      atomicAdd(&red[o + 0], a00); atomicAdd(&red[o + 1], a01); atomicAdd(&red[o + 2], a02);
      atomicAdd(&red[o + 3], a10); atomicAdd(&red[o + 4], a11); atomicAdd(&red[o + 5], a12);
      atomicAdd(&red[o + 6], a20); atomicAdd(&red[o + 7], a21); atomicAdd(&red[o + 8], a22);
    } else {
      const int o = NGRAM + (task - NPAIR) * 3;
      atomicAdd(&red[o + 0], a00); atomicAdd(&red[o + 1], a10); atomicAdd(&red[o + 2], a20);
    }
  }
  __syncthreads();
  for (int e = tid; e < NSTAT; e += 256) atomicAdd(&ws[e], red[e]);
}

__device__ __forceinline__ float qform(const float* G, int p,
                                       const float* wa, const float* wb) {
  float t = 0.f;
#pragma unroll
  for (int j = 0; j < 3; j++)
#pragma unroll
    for (int jp = 0; jp < 3; jp++)
      t = fmaf(wa[j] * wb[jp], G[p * 9 + j * 3 + jp], t);
  return t;
}

__global__ __launch_bounds__(256) void finalize_kernel(
    const float* __restrict__ w1, const float* __restrict__ w2,
    const float* __restrict__ g1, const float* __restrict__ be1,
    const float* __restrict__ g2, const float* __restrict__ be2,
    float* __restrict__ ws) {
  __shared__ float G[NSTAT];
  const int tid = threadIdx.x;
  for (int e = tid; e < NSTAT; e += 256) G[e] = ws[e];
  __syncthreads();
  const int f = tid;
  if (f >= NF) return;
  float w1r[9], w2r[15];
#pragma unroll
  for (int j = 0; j < 9; j++)  w1r[j] = w1[f * 9 + j];
#pragma unroll
  for (int j = 0; j < 15; j++) w2r[j] = w2[f * 15 + j];
  const float invN = 1.0f / (float)(BB * W_OUT);
  const float* Sm = &G[NGRAM];

  float m1 = 0.f;
#pragma unroll
  for (int r = 0; r < 3; r++)
#pragma unroll
    for (int j = 0; j < 3; j++) m1 = fmaf(w1r[r * 3 + j], Sm[r * 3 + j], m1);
  float q1 = qform(G, 0, w1r, w1r) + 2.f * qform(G, 1, w1r, w1r + 3)
           + 2.f * qform(G, 2, w1r, w1r + 6) + qform(G, 3, w1r + 3, w1r + 3)
           + 2.f * qform(G, 4, w1r + 3, w1r + 6) + qform(G, 5, w1r + 6, w1r + 6);
  m1 *= invN;
  float v1 = q1 * invN - m1 * m1;
  float sc1 = g1[f] * rsqrtf(v1 + EPS);
  float sh1 = be1[f] - m1 * sc1;

  float mc = 0.f;
#pragma unroll
  for (int r = 0; r < 3; r++)
#pragma unroll
    for (int j = 0; j < 3; j++) mc = fmaf(w2r[r * 3 + j], Sm[r * 3 + j], mc);
  float qc = qform(G, 0, w2r, w2r) + 2.f * qform(G, 1, w2r, w2r + 3)
           + 2.f * qform(G, 2, w2r, w2r + 6) + qform(G, 3, w2r + 3, w2r + 3)
           + 2.f * qform(G, 4, w2r + 3, w2r + 6) + qform(G, 5, w2r + 6, w2r + 6);
  const float* wA = w2r + 9;
  const float* wB = w2r + 12;
  float sc2o[3], sh2o[3];
#pragma unroll
  for (int k = 0; k < 3; k++) {
    const int a = 3 + 2 * k, b = 4 + 2 * k, p0 = 6 + 9 * k;
    float m2 = mc;
#pragma unroll
    for (int j = 0; j < 3; j++) {
      m2 = fmaf(wA[j], Sm[a * 3 + j], m2);
      m2 = fmaf(wB[j], Sm[b * 3 + j], m2);
    }
    float q2 = qc
      + 2.f * (qform(G, p0 + 0, w2r, wA) + qform(G, p0 + 1, w2r + 3, wA)
             + qform(G, p0 + 2, w2r + 6, wA) + qform(G, p0 + 3, w2r, wB)
             + qform(G, p0 + 4, w2r + 3, wB) + qform(G, p0 + 5, w2r + 6, wB))
      + qform(G, p0 + 6, wA, wA) + 2.f * qform(G, p0 + 7, wA, wB)
      + qform(G, p0 + 8, wB, wB);
    m2 *= invN;
    float v2 = q2 * invN - m2 * m2;
    float sck = g2[f] * rsqrtf(v2 + EPS);
    sc2o[k] = sck;
    sh2o[k] = be2[f] - m2 * sck;
  }

  float* pp = ws + PKD_OFF + f * PKD_STRIDE;
#pragma unroll
  for (int j = 0; j < 9; j++)  pp[j] = w1r[j];
#pragma unroll
  for (int j = 0; j < 15; j++) pp[9 + j] = w2r[j];
  pp[24] = sc1;
  pp[25] = sh1;
#pragma unroll
  for (int k = 0; k < 3; k++) { pp[26 + k] = sc2o[k]; pp[29 + k] = sh2o[k]; }
}

// ---------------- main: thread = x position, f-loop split across FS blocks --
template <int FSN, bool DIRECT>
__global__ __launch_bounds__(256, 4) void main_x_kernel(
    const int* __restrict__ xb, const float* __restrict__ er,
    const float* __restrict__ ev, const float* __restrict__ fcw,
    const float* __restrict__ fcb, const float* __restrict__ ws,
    float* __restrict__ outp) {
  __shared__ f32x2 hsI[2][9][132];     // paired samples, cols 128..131 zeroed
  __shared__ const float* volatile rowp[SPB][9];
  __shared__ f32x2 red[4];
  const int tid = threadIdx.x;
  const int p = tid >> 7;              // pair index (0,1)
  const int x = tid & 127;             // output position (0..125 active)
  const int bq = blockIdx.x / FSN;     // sample-quad
  const int fs = blockIdx.x % FSN;     // f-slice
  const int base = bq * SPB;
  const int f0 = fs * (NF / FSN);

  if (tid < SPB * 9) {
    int s = tid / 9, r = tid % 9;
    const int* xr = xb + (size_t)(base + s) * 10;
    const float* q;
    if (r == 0)      q = ev + (size_t)xr[1] * EMB;
    else if (r == 1) q = er + (size_t)xr[0] * EMB;
    else if (r == 2) q = ev + (size_t)xr[3] * EMB;
    else {
      int k = (r - 3) >> 1;
      q = ((r - 3) & 1) ? ev + (size_t)xr[5 + 2 * k] * EMB
                        : er + (size_t)xr[4 + 2 * k] * EMB;
    }
    rowp[s][r] = q;
  }
  __syncthreads();
  for (int e = tid; e < 2 * 9 * 132; e += 256) {
    int pp_ = e / (9 * 132), rem = e % (9 * 132);
    int r = rem / 132, col = rem % 132;
    const float* ra = rowp[2 * pp_][r];
    const float* rb = rowp[2 * pp_ + 1][r];
    hsI[pp_][r][col] = (col < EMB) ? (f32x2){ra[col], rb[col]} : (f32x2){0.f, 0.f};
  }
  __syncthreads();

  // pull this thread's 9x3 window into registers and FORCE it to stay there
  f32x2 A[9], Bq[9], C[9];
#pragma unroll
  for (int r = 0; r < 9; r++) {
    A[r]  = hsI[p][r][x];
    Bq[r] = hsI[p][r][x + 1];
    C[r]  = hsI[p][r][x + 2];
  }
#pragma unroll
  for (int r = 0; r < 9; r++) {
    asm volatile("" : "+v"(A[r]), "+v"(Bq[r]), "+v"(C[r]));
  }

  const float* __restrict__ pkd = ws + PKD_OFF;
  const bool valid = (x < W_OUT);
  f32x2 acc = {0.f, 0.f};

#pragma unroll 2
  for (int f = f0; f < f0 + NF / FSN; ++f) {
    const float* __restrict__ pp = pkd + f * PKD_STRIDE;  // uniform -> s_load
    float wp[32];
#pragma unroll
    for (int j = 0; j < 32; j++) wp[j] = pp[j];
    float fcv = valid ? fcw[f * W_OUT + x] : 0.f;         // coalesced

    f32x2 r1 = A[0] * wp[0];
    r1 = fma2(Bq[0], wp[1], r1); r1 = fma2(C[0], wp[2], r1);
    r1 = fma2(A[1], wp[3], r1);  r1 = fma2(Bq[1], wp[4], r1);
    r1 = fma2(C[1], wp[5], r1);  r1 = fma2(A[2], wp[6], r1);
    r1 = fma2(Bq[2], wp[7], r1); r1 = fma2(C[2], wp[8], r1);

    f32x2 cm = A[0] * wp[9];
    cm = fma2(Bq[0], wp[10], cm); cm = fma2(C[0], wp[11], cm);
    cm = fma2(A[1], wp[12], cm);  cm = fma2(Bq[1], wp[13], cm);
    cm = fma2(C[1], wp[14], cm);  cm = fma2(A[2], wp[15], cm);
    cm = fma2(Bq[2], wp[16], cm); cm = fma2(C[2], wp[17], cm);

    f32x2 rk0 = fma2(A[3], wp[18], cm);
    rk0 = fma2(Bq[3], wp[19], rk0); rk0 = fma2(C[3], wp[20], rk0);
    rk0 = fma2(A[4], wp[21], rk0);  rk0 = fma2(Bq[4], wp[22], rk0);
    rk0 = fma2(C[4], wp[23], rk0);

    f32x2 rk1 = fma2(A[5], wp[18], cm);
    rk1 = fma2(Bq[5], wp[19], rk1); rk1 = fma2(C[5], wp[20], rk1);
    rk1 = fma2(A[6], wp[21], rk1);  rk1 = fma2(Bq[6], wp[22], rk1);
    rk1 = fma2(C[6], wp[23], rk1);

    f32x2 rk2 = fma2(A[7], wp[18], cm);
    rk2 = fma2(Bq[7], wp[19], rk2); rk2 = fma2(C[7], wp[20], rk2);
    rk2 = fma2(A[8], wp[21], rk2);  rk2 = fma2(Bq[8], wp[22], rk2);
    rk2 = fma2(C[8], wp[23], rk2);

    f32x2 mv = fmss(r1, wp[24], wp[25]);
    mv = min2(mv, fmss(rk0, wp[26], wp[29]));
    mv = min2(mv, fmss(rk1, wp[27], wp[30]));
    mv = min2(mv, fmss(rk2, wp[28], wp[31]));
    mv = __builtin_elementwise_max(mv, (f32x2){0.f, 0.f});
    acc = fma2(mv, fcv, acc);
  }

  float ax = acc.x, ay = acc.y;
#pragma unroll
  for (int off = 32; off > 0; off >>= 1) {
    ax += __shfl_down(ax, off, 64);
    ay += __shfl_down(ay, off, 64);
  }
  if ((tid & 63) == 0) red[tid >> 6] = (f32x2){ax, ay};
  __syncthreads();
  if (tid < 4) {
    int pr = tid >> 1, c = tid & 1;
    f32x2 r0 = red[2 * pr], r1v = red[2 * pr + 1];
    float v = (c ? (r0.y + r1v.y) : (r0.x + r1v.x));
    if (DIRECT) outp[base + 2 * pr + c] = v + fcb[0];
    else        outp[fs * BB + base + 2 * pr + c] = v;   // partials in ws
  }
}

__global__ __launch_bounds__(256) void reduce_out(
    const float* __restrict__ part, const float* __restrict__ fcb,
    float* __restrict__ out) {
  int b = blockIdx.x * 256 + threadIdx.x;
  if (b < BB) {
    float s = part[b];
#pragma unroll
    for (int k = 1; k < FS; k++) s += part[k * BB + b];
    out[b] = s + fcb[0];
  }
}

extern "C" void kernel_launch(void* const* d_in, const int* in_sizes, int n_in,
                              void* d_out, int out_size, void* d_ws, size_t ws_size,
                              hipStream_t stream) {
  const int* xb    = (const int*)d_in[0];
  const float* er  = (const float*)d_in[3];
  const float* ev  = (const float*)d_in[4];
  const float* w1  = (const float*)d_in[5];
  const float* g1  = (const float*)d_in[7];
  const float* be1 = (const float*)d_in[8];
  const float* w2  = (const float*)d_in[9];
  const float* g2  = (const float*)d_in[11];
  const float* be2 = (const float*)d_in[12];
  const float* fcw = (const float*)d_in[13];
  const float* fcb = (const float*)d_in[14];
  float* ws  = (float*)d_ws;
  float* out = (float*)d_out;

  const size_t need_part = (size_t)(PART_OFF + FS * BB) * sizeof(float);
  const int use_part = (ws_size >= need_part) ? 1 : 0;

  hipMemsetAsync(ws, 0, NSTAT * sizeof(float), stream);
  hipLaunchKernelGGL(stats_kernel, dim3(STATS_BLOCKS * 2), dim3(256), 0, stream,
                     xb, er, ev, ws);
  hipLaunchKernelGGL(finalize_kernel, dim3(1), dim3(256), 0, stream,
                     w1, w2, g1, be1, g2, be2, ws);
  if (use_part) {
    hipLaunchKernelGGL((main_x_kernel<FS, false>), dim3(MAIN_BLOCKS * FS),
                       dim3(256), 0, stream, xb, er, ev, fcw, fcb, ws,
                       ws + PART_OFF);
    hipLaunchKernelGGL(reduce_out, dim3((BB + 255) / 256), dim3(256), 0, stream,
                       ws + PART_OFF, fcb, out);
  } else {
    hipLaunchKernelGGL((main_x_kernel<1, true>), dim3(MAIN_BLOCKS),
                       dim3(256), 0, stream, xb, er, ev, fcw, fcb, ws, out);
  }
}

// Round 7
// 93.688 us; speedup vs baseline: 1.0211x; 1.0211x over previous
//
#include <hip/hip_runtime.h>

#define BB 2048
#define EMB 128
#define NF 200
#define W_OUT 126
#define EPS 1e-5f

#define SPB 4                     // samples per block (2 pairs)
#define FS 4                      // f-split factor
#define MAIN_BLOCKS (BB / SPB)    // 512 sample-quads

#define SLOTS 3
#define STHREADS 128
#define NTASK 42
#define NPAIR 33
#define NGRAM 297
#define NSTAT 324
#define STATS_BLOCKS 683          // 683*3 = 2049 >= 2048

#define PKD_OFF 3456              // float offset of packed per-f params in ws
#define PKD_STRIDE 32
#define PART_OFF 16384            // float offset of per-fs partial dot products

typedef float f32x2 __attribute__((ext_vector_type(2)));

__device__ __forceinline__ f32x2 fma2(f32x2 a, float s, f32x2 c) {
  return __builtin_elementwise_fma(a, (f32x2){s, s}, c);
}
__device__ __forceinline__ f32x2 fmss(f32x2 a, float s, float sh) {
  return __builtin_elementwise_fma(a, (f32x2){s, s}, (f32x2){sh, sh});
}
__device__ __forceinline__ f32x2 min2(f32x2 a, f32x2 b) {
  return __builtin_elementwise_min(a, b);
}

// ---------------- stats (Gram): SLOTS=3, 128 threads, 683 blocks ------------
__device__ __constant__ unsigned char PA_t[NTASK] = {
  0,0,0,1,1,2,
  0,1,2,0,1,2, 3,3,4,
  0,1,2,0,1,2, 5,5,6,
  0,1,2,0,1,2, 7,7,8,
  0,1,2,3,4,5,6,7,8};
__device__ __constant__ unsigned char PB_t[NTASK] = {
  0,1,2,1,2,2,
  3,3,3,4,4,4, 3,4,4,
  5,5,5,6,6,6, 5,6,6,
  7,7,7,8,8,8, 7,8,8,
  9,9,9,9,9,9,9,9,9};

__global__ __launch_bounds__(STHREADS, 8) void stats_kernel(
    const int* __restrict__ xb, const float* __restrict__ er,
    const float* __restrict__ ev, float* __restrict__ ws) {
  __shared__ float hs[SLOTS][10][132];
  __shared__ const float* volatile rowp[SLOTS][9];
  __shared__ float red[NSTAT];
  const int tid = threadIdx.x;
  const int base = blockIdx.x * SLOTS;

  for (int e = tid; e < SLOTS * EMB; e += STHREADS) hs[e / EMB][9][e & 127] = 1.0f;
  for (int e = tid; e < NSTAT; e += STHREADS) red[e] = 0.f;

  if (tid < SLOTS * 9) {
    int s = tid / 9, r = tid % 9;
    int b = base + s;
    const float* p = nullptr;
    if (b < BB) {
      const int* xr = xb + b * 10;
      if (r == 0)      p = ev + (size_t)xr[1] * EMB;
      else if (r == 1) p = er + (size_t)xr[0] * EMB;
      else if (r == 2) p = ev + (size_t)xr[3] * EMB;
      else {
        int k = (r - 3) >> 1;
        p = ((r - 3) & 1) ? ev + (size_t)xr[5 + 2 * k] * EMB
                          : er + (size_t)xr[4 + 2 * k] * EMB;
      }
    }
    rowp[s][r] = p;
  }
  __syncthreads();
  for (int e = tid; e < SLOTS * 9 * EMB; e += STHREADS) {
    int s = e / (9 * EMB), rem = e % (9 * EMB);
    int r = rem >> 7, col = rem & 127;
    const float* p = (const float*)rowp[s][r];
    hs[s][r][col] = p ? p[col] : 0.f;
  }
  __syncthreads();

  const int slot = tid / NTASK;
  const int task = tid % NTASK;
  if (tid < SLOTS * NTASK) {
    const float* A  = &hs[slot][PA_t[task]][0];
    const float* Bq = &hs[slot][PB_t[task]][0];
    float a00 = 0.f, a01 = 0.f, a02 = 0.f;
    float a10 = 0.f, a11 = 0.f, a12 = 0.f;
    float a20 = 0.f, a21 = 0.f, a22 = 0.f;
    float wa0 = A[0], wa1 = A[1], wb0 = Bq[0], wb1 = Bq[1];
#pragma unroll 3
    for (int x = 0; x < W_OUT; ++x) {
      float wa2 = A[x + 2], wb2 = Bq[x + 2];
      a00 = fmaf(wa0, wb0, a00); a01 = fmaf(wa0, wb1, a01); a02 = fmaf(wa0, wb2, a02);
      a10 = fmaf(wa1, wb0, a10); a11 = fmaf(wa1, wb1, a11); a12 = fmaf(wa1, wb2, a12);
      a20 = fmaf(wa2, wb0, a20); a21 = fmaf(wa2, wb1, a21); a22 = fmaf(wa2, wb2, a22);
      wa0 = wa1; wa1 = wa2; wb0 = wb1; wb1 = wb2;
    }
    if (task < NPAIR) {
      const int o = task * 9;
      atomicAdd(&red[o + 0], a00); atomicAdd(&red[o + 1], a01); atomicAdd(&red[o + 2], a02);
      atomicAdd(&red[o + 3], a10); atomicAdd(&red[o + 4], a11); atomicAdd(&red[o + 5], a12);
      atomicAdd(&red[o + 6], a20); atomicAdd(&red[o + 7], a21); atomicAdd(&red[o + 8], a22);
    } else {
      const int o = NGRAM + (task - NPAIR) * 3;
      atomicAdd(&red[o + 0], a00); atomicAdd(&red[o + 1], a10); atomicAdd(&red[o + 2], a20);
    }
  }
  __syncthreads();
  for (int e = tid; e < NSTAT; e += STHREADS) atomicAdd(&ws[e], red[e]);
}

__device__ __forceinline__ float qform(const float* G, int p,
                                       const float* wa, const float* wb) {
  float t = 0.f;
#pragma unroll
  for (int j = 0; j < 3; j++)
#pragma unroll
    for (int jp = 0; jp < 3; jp++)
      t = fmaf(wa[j] * wb[jp], G[p * 9 + j * 3 + jp], t);
  return t;
}

// pkd layout per f (stride 32):
// [0..8]  w1r*sc1   [9..23] w2r   [24] sh1
// [25..27] sc2[k]   [28..30] sh2[k]
__global__ __launch_bounds__(256) void finalize_kernel(
    const float* __restrict__ w1, const float* __restrict__ w2,
    const float* __restrict__ g1, const float* __restrict__ be1,
    const float* __restrict__ g2, const float* __restrict__ be2,
    float* __restrict__ ws) {
  __shared__ float G[NSTAT];
  const int tid = threadIdx.x;
  for (int e = tid; e < NSTAT; e += 256) G[e] = ws[e];
  __syncthreads();
  const int f = tid;
  if (f >= NF) return;
  float w1r[9], w2r[15];
#pragma unroll
  for (int j = 0; j < 9; j++)  w1r[j] = w1[f * 9 + j];
#pragma unroll
  for (int j = 0; j < 15; j++) w2r[j] = w2[f * 15 + j];
  const float invN = 1.0f / (float)(BB * W_OUT);
  const float* Sm = &G[NGRAM];

  float m1 = 0.f;
#pragma unroll
  for (int r = 0; r < 3; r++)
#pragma unroll
    for (int j = 0; j < 3; j++) m1 = fmaf(w1r[r * 3 + j], Sm[r * 3 + j], m1);
  float q1 = qform(G, 0, w1r, w1r) + 2.f * qform(G, 1, w1r, w1r + 3)
           + 2.f * qform(G, 2, w1r, w1r + 6) + qform(G, 3, w1r + 3, w1r + 3)
           + 2.f * qform(G, 4, w1r + 3, w1r + 6) + qform(G, 5, w1r + 6, w1r + 6);
  m1 *= invN;
  float v1 = q1 * invN - m1 * m1;
  float sc1 = g1[f] * rsqrtf(v1 + EPS);
  float sh1 = be1[f] - m1 * sc1;

  float mc = 0.f;
#pragma unroll
  for (int r = 0; r < 3; r++)
#pragma unroll
    for (int j = 0; j < 3; j++) mc = fmaf(w2r[r * 3 + j], Sm[r * 3 + j], mc);
  float qc = qform(G, 0, w2r, w2r) + 2.f * qform(G, 1, w2r, w2r + 3)
           + 2.f * qform(G, 2, w2r, w2r + 6) + qform(G, 3, w2r + 3, w2r + 3)
           + 2.f * qform(G, 4, w2r + 3, w2r + 6) + qform(G, 5, w2r + 6, w2r + 6);
  const float* wA = w2r + 9;
  const float* wB = w2r + 12;
  float sc2o[3], sh2o[3];
#pragma unroll
  for (int k = 0; k < 3; k++) {
    const int a = 3 + 2 * k, b = 4 + 2 * k, p0 = 6 + 9 * k;
    float m2 = mc;
#pragma unroll
    for (int j = 0; j < 3; j++) {
      m2 = fmaf(wA[j], Sm[a * 3 + j], m2);
      m2 = fmaf(wB[j], Sm[b * 3 + j], m2);
    }
    float q2 = qc
      + 2.f * (qform(G, p0 + 0, w2r, wA) + qform(G, p0 + 1, w2r + 3, wA)
             + qform(G, p0 + 2, w2r + 6, wA) + qform(G, p0 + 3, w2r, wB)
             + qform(G, p0 + 4, w2r + 3, wB) + qform(G, p0 + 5, w2r + 6, wB))
      + qform(G, p0 + 6, wA, wA) + 2.f * qform(G, p0 + 7, wA, wB)
      + qform(G, p0 + 8, wB, wB);
    m2 *= invN;
    float v2 = q2 * invN - m2 * m2;
    float sck = g2[f] * rsqrtf(v2 + EPS);
    sc2o[k] = sck;
    sh2o[k] = be2[f] - m2 * sck;
  }

  float* pp = ws + PKD_OFF + f * PKD_STRIDE;
#pragma unroll
  for (int j = 0; j < 9; j++)  pp[j] = w1r[j] * sc1;   // sc1 folded into w1
#pragma unroll
  for (int j = 0; j < 15; j++) pp[9 + j] = w2r[j];
  pp[24] = sh1;
#pragma unroll
  for (int k = 0; k < 3; k++) { pp[25 + k] = sc2o[k]; pp[28 + k] = sh2o[k]; }
}

// ---------------- main: window direct-to-registers from global --------------
__device__ __forceinline__ const float* rowptr(const int* __restrict__ xr, int r,
                                               const float* __restrict__ er,
                                               const float* __restrict__ ev) {
  if (r == 0) return ev + (size_t)xr[1] * EMB;
  if (r == 1) return er + (size_t)xr[0] * EMB;
  if (r == 2) return ev + (size_t)xr[3] * EMB;
  const int k = (r - 3) >> 1;
  return ((r - 3) & 1) ? ev + (size_t)xr[5 + 2 * k] * EMB
                       : er + (size_t)xr[4 + 2 * k] * EMB;
}

template <int FSN, bool DIRECT>
__global__ __launch_bounds__(256, 4) void main_x_kernel(
    const int* __restrict__ xb, const float* __restrict__ er,
    const float* __restrict__ ev, const float* __restrict__ fcw,
    const float* __restrict__ fcb, const float* __restrict__ ws,
    float* __restrict__ outp) {
  __shared__ f32x2 red[4];
  const int tid = threadIdx.x;
  const int p = tid >> 7;              // pair index (0,1)
  const int x = tid & 127;             // output position (0..125 active)
  const int bq = blockIdx.x / FSN;     // sample-quad
  const int fs = blockIdx.x % FSN;     // f-slice
  const int base = bq * SPB;
  const int f0 = fs * (NF / FSN);

  const int* xrA = xb + (size_t)(base + 2 * p) * 10;
  const int* xrB = xb + (size_t)(base + 2 * p + 1) * 10;
  const int c1 = (x + 1 < 128) ? x + 1 : 127;   // clamp: avoid OOB past row
  const int c2 = (x + 2 < 128) ? x + 2 : 127;   // (inactive lanes only)

  // 9x3 window for both samples, straight into VGPRs (no LDS copy exists)
  f32x2 A[9], Bq[9], C[9];
#pragma unroll
  for (int r = 0; r < 9; r++) {
    const float* ra = rowptr(xrA, r, er, ev);
    const float* rb = rowptr(xrB, r, er, ev);
    A[r]  = (f32x2){ra[x],  rb[x]};
    Bq[r] = (f32x2){ra[c1], rb[c1]};
    C[r]  = (f32x2){ra[c2], rb[c2]};
  }

  const float* __restrict__ pkd = ws + PKD_OFF;
  const int xc = (x < W_OUT) ? x : W_OUT - 1;
  f32x2 acc = {0.f, 0.f};

#pragma unroll 2
  for (int f = f0; f < f0 + NF / FSN; ++f) {
    const float* __restrict__ pp = pkd + f * PKD_STRIDE;  // uniform -> s_load
    float wp[32];
#pragma unroll
    for (int j = 0; j < 32; j++) wp[j] = pp[j];
    const float fcv = fcw[f * W_OUT + xc];                // coalesced, L2

    f32x2 mv = {wp[24], wp[24]};                          // bn1: sh1 + conv(w1*sc1)
    mv = fma2(A[0], wp[0], mv);  mv = fma2(Bq[0], wp[1], mv);
    mv = fma2(C[0], wp[2], mv);  mv = fma2(A[1], wp[3], mv);
    mv = fma2(Bq[1], wp[4], mv); mv = fma2(C[1], wp[5], mv);
    mv = fma2(A[2], wp[6], mv);  mv = fma2(Bq[2], wp[7], mv);
    mv = fma2(C[2], wp[8], mv);

    f32x2 cm = A[0] * wp[9];
    cm = fma2(Bq[0], wp[10], cm); cm = fma2(C[0], wp[11], cm);
    cm = fma2(A[1], wp[12], cm);  cm = fma2(Bq[1], wp[13], cm);
    cm = fma2(C[1], wp[14], cm);  cm = fma2(A[2], wp[15], cm);
    cm = fma2(Bq[2], wp[16], cm); cm = fma2(C[2], wp[17], cm);

    f32x2 rk0 = fma2(A[3], wp[18], cm);
    rk0 = fma2(Bq[3], wp[19], rk0); rk0 = fma2(C[3], wp[20], rk0);
    rk0 = fma2(A[4], wp[21], rk0);  rk0 = fma2(Bq[4], wp[22], rk0);
    rk0 = fma2(C[4], wp[23], rk0);

    f32x2 rk1 = fma2(A[5], wp[18], cm);
    rk1 = fma2(Bq[5], wp[19], rk1); rk1 = fma2(C[5], wp[20], rk1);
    rk1 = fma2(A[6], wp[21], rk1);  rk1 = fma2(Bq[6], wp[22], rk1);
    rk1 = fma2(C[6], wp[23], rk1);

    f32x2 rk2 = fma2(A[7], wp[18], cm);
    rk2 = fma2(Bq[7], wp[19], rk2); rk2 = fma2(C[7], wp[20], rk2);
    rk2 = fma2(A[8], wp[21], rk2);  rk2 = fma2(Bq[8], wp[22], rk2);
    rk2 = fma2(C[8], wp[23], rk2);

    mv = min2(mv, fmss(rk0, wp[25], wp[28]));
    mv = min2(mv, fmss(rk1, wp[26], wp[29]));
    mv = min2(mv, fmss(rk2, wp[27], wp[30]));
    mv = __builtin_elementwise_max(mv, (f32x2){0.f, 0.f});
    acc = fma2(mv, fcv, acc);
  }

  if (x >= W_OUT) acc = (f32x2){0.f, 0.f};   // mask inactive lanes once

  float ax = acc.x, ay = acc.y;
#pragma unroll
  for (int off = 32; off > 0; off >>= 1) {
    ax += __shfl_down(ax, off, 64);
    ay += __shfl_down(ay, off, 64);
  }
  if ((tid & 63) == 0) red[tid >> 6] = (f32x2){ax, ay};
  __syncthreads();
  if (tid < 4) {
    int pr = tid >> 1, c = tid & 1;
    f32x2 r0 = red[2 * pr], r1v = red[2 * pr + 1];
    float v = (c ? (r0.y + r1v.y) : (r0.x + r1v.x));
    if (DIRECT) outp[base + 2 * pr + c] = v + fcb[0];
    else        outp[fs * BB + base + 2 * pr + c] = v;   // partials in ws
  }
}

__global__ __launch_bounds__(256) void reduce_out(
    const float* __restrict__ part, const float* __restrict__ fcb,
    float* __restrict__ out) {
  int b = blockIdx.x * 256 + threadIdx.x;
  if (b < BB) {
    float s = part[b];
#pragma unroll
    for (int k = 1; k < FS; k++) s += part[k * BB + b];
    out[b] = s + fcb[0];
  }
}

extern "C" void kernel_launch(void* const* d_in, const int* in_sizes, int n_in,
                              void* d_out, int out_size, void* d_ws, size_t ws_size,
                              hipStream_t stream) {
  const int* xb    = (const int*)d_in[0];
  const float* er  = (const float*)d_in[3];
  const float* ev  = (const float*)d_in[4];
  const float* w1  = (const float*)d_in[5];
  const float* g1  = (const float*)d_in[7];
  const float* be1 = (const float*)d_in[8];
  const float* w2  = (const float*)d_in[9];
  const float* g2  = (const float*)d_in[11];
  const float* be2 = (const float*)d_in[12];
  const float* fcw = (const float*)d_in[13];
  const float* fcb = (const float*)d_in[14];
  float* ws  = (float*)d_ws;
  float* out = (float*)d_out;

  const size_t need_part = (size_t)(PART_OFF + FS * BB) * sizeof(float);
  const int use_part = (ws_size >= need_part) ? 1 : 0;

  hipMemsetAsync(ws, 0, NSTAT * sizeof(float), stream);
  hipLaunchKernelGGL(stats_kernel, dim3(STATS_BLOCKS), dim3(STHREADS), 0, stream,
                     xb, er, ev, ws);
  hipLaunchKernelGGL(finalize_kernel, dim3(1), dim3(256), 0, stream,
                     w1, w2, g1, be1, g2, be2, ws);
  if (use_part) {
    hipLaunchKernelGGL((main_x_kernel<FS, false>), dim3(MAIN_BLOCKS * FS),
                       dim3(256), 0, stream, xb, er, ev, fcw, fcb, ws,
                       ws + PART_OFF);
    hipLaunchKernelGGL(reduce_out, dim3((BB + 255) / 256), dim3(256), 0, stream,
                       ws + PART_OFF, fcb, out);
  } else {
    hipLaunchKernelGGL((main_x_kernel<1, true>), dim3(MAIN_BLOCKS),
                       dim3(256), 0, stream, xb, er, ev, fcw, fcb, ws, out);
  }
}

// Round 8
// 62.198 us; speedup vs baseline: 1.5381x; 1.5063x over previous
//
#include <hip/hip_runtime.h>

#define BB 2048
#define EMB 128
#define NF 200
#define W_OUT 126
#define EPS 1e-5f

// ---- stats (Gram) ----
#define SLOTS 6
#define NTASK 42
#define NPAIR 33
#define NGRAM 297
#define NSTAT 324
#define STATS_BLOCKS 342

// ---- mfma main ----
#define SPBM 4                    // samples per block (= waves per block)
#define MAIN_BLOCKS (BB / SPBM)   // 512
#define AW_OFF 512                // float offset in ws of f16 A-matrix (800x32 halfs)

typedef _Float16 half8 __attribute__((ext_vector_type(8)));
typedef float f32x4v __attribute__((ext_vector_type(4)));

// ---------------- stats (Gram): R5-proven config ----------------------------
__device__ __constant__ unsigned char PA_t[NTASK] = {
  0,0,0,1,1,2,
  0,1,2,0,1,2, 3,3,4,
  0,1,2,0,1,2, 5,5,6,
  0,1,2,0,1,2, 7,7,8,
  0,1,2,3,4,5,6,7,8};
__device__ __constant__ unsigned char PB_t[NTASK] = {
  0,1,2,1,2,2,
  3,3,3,4,4,4, 3,4,4,
  5,5,5,6,6,6, 5,6,6,
  7,7,7,8,8,8, 7,8,8,
  9,9,9,9,9,9,9,9,9};

__global__ __launch_bounds__(256, 4) void stats_kernel(
    const int* __restrict__ xb, const float* __restrict__ er,
    const float* __restrict__ ev, float* __restrict__ ws) {
  __shared__ float hs[SLOTS][10][132];
  __shared__ const float* volatile rowp[SLOTS][9];
  __shared__ float red[NSTAT];
  const int tid = threadIdx.x;
  for (int e = tid; e < SLOTS * EMB; e += 256) hs[e / EMB][9][e & 127] = 1.0f;
  for (int e = tid; e < NSTAT; e += 256) red[e] = 0.f;

  const int base = blockIdx.x * SLOTS;
  if (tid < SLOTS * 9) {
    int s = tid / 9, r = tid % 9;
    int b = base + s;
    const float* p = nullptr;
    if (b < BB) {
      const int* xr = xb + b * 10;
      if (r == 0)      p = ev + (size_t)xr[1] * EMB;
      else if (r == 1) p = er + (size_t)xr[0] * EMB;
      else if (r == 2) p = ev + (size_t)xr[3] * EMB;
      else {
        int k = (r - 3) >> 1;
        p = ((r - 3) & 1) ? ev + (size_t)xr[5 + 2 * k] * EMB
                          : er + (size_t)xr[4 + 2 * k] * EMB;
      }
    }
    rowp[s][r] = p;
  }
  __syncthreads();
  for (int e = tid; e < SLOTS * 9 * EMB; e += 256) {
    int s = e / (9 * EMB), rem = e % (9 * EMB);
    int r = rem >> 7, col = rem & 127;
    const float* p = (const float*)rowp[s][r];
    hs[s][r][col] = p ? p[col] : 0.f;
  }
  __syncthreads();

  const int slot = tid / NTASK;
  const int task = tid % NTASK;
  if (tid < SLOTS * NTASK) {
    const float* A  = &hs[slot][PA_t[task]][0];
    const float* Bq = &hs[slot][PB_t[task]][0];
    float a00 = 0.f, a01 = 0.f, a02 = 0.f;
    float a10 = 0.f, a11 = 0.f, a12 = 0.f;
    float a20 = 0.f, a21 = 0.f, a22 = 0.f;
    float wa0 = A[0], wa1 = A[1], wb0 = Bq[0], wb1 = Bq[1];
#pragma unroll 3
    for (int x = 0; x < W_OUT; ++x) {
      float wa2 = A[x + 2], wb2 = Bq[x + 2];
      a00 = fmaf(wa0, wb0, a00); a01 = fmaf(wa0, wb1, a01); a02 = fmaf(wa0, wb2, a02);
      a10 = fmaf(wa1, wb0, a10); a11 = fmaf(wa1, wb1, a11); a12 = fmaf(wa1, wb2, a12);
      a20 = fmaf(wa2, wb0, a20); a21 = fmaf(wa2, wb1, a21); a22 = fmaf(wa2, wb2, a22);
      wa0 = wa1; wa1 = wa2; wb0 = wb1; wb1 = wb2;
    }
    if (task < NPAIR) {
      const int o = task * 9;
      atomicAdd(&red[o + 0], a00); atomicAdd(&red[o + 1], a01); atomicAdd(&red[o + 2], a02);
      atomicAdd(&red[o + 3], a10); atomicAdd(&red[o + 4], a11); atomicAdd(&red[o + 5], a12);
      atomicAdd(&red[o + 6], a20); atomicAdd(&red[o + 7], a21); atomicAdd(&red[o + 8], a22);
    } else {
      const int o = NGRAM + (task - NPAIR) * 3;
      atomicAdd(&red[o + 0], a00); atomicAdd(&red[o + 1], a10); atomicAdd(&red[o + 2], a20);
    }
  }
  __syncthreads();
  for (int e = tid; e < NSTAT; e += 256) atomicAdd(&ws[e], red[e]);
}

__device__ __forceinline__ float qform(const float* G, int p,
                                       const float* wa, const float* wb) {
  float t = 0.f;
#pragma unroll
  for (int j = 0; j < 3; j++)
#pragma unroll
    for (int jp = 0; jp < 3; jp++)
      t = fmaf(wa[j] * wb[jp], G[p * 9 + j * 3 + jp], t);
  return t;
}

// finalize: gram -> bn params -> f16 A-matrix (M = 4f+conv, K = 32)
// K taps: k=3r+j -> h[r][x+j]; k27 = ones-row (carries bn shift); k28..31 = 0
__global__ __launch_bounds__(256) void finalize_kernel(
    const float* __restrict__ w1, const float* __restrict__ w2,
    const float* __restrict__ g1, const float* __restrict__ be1,
    const float* __restrict__ g2, const float* __restrict__ be2,
    float* __restrict__ ws) {
  __shared__ float G[NSTAT];
  const int tid = threadIdx.x;
  for (int e = tid; e < NSTAT; e += 256) G[e] = ws[e];
  __syncthreads();
  const int f = tid;
  if (f >= NF) return;
  float w1r[9], w2r[15];
#pragma unroll
  for (int j = 0; j < 9; j++)  w1r[j] = w1[f * 9 + j];
#pragma unroll
  for (int j = 0; j < 15; j++) w2r[j] = w2[f * 15 + j];
  const float invN = 1.0f / (float)(BB * W_OUT);
  const float* Sm = &G[NGRAM];

  float m1 = 0.f;
#pragma unroll
  for (int r = 0; r < 3; r++)
#pragma unroll
    for (int j = 0; j < 3; j++) m1 = fmaf(w1r[r * 3 + j], Sm[r * 3 + j], m1);
  float q1 = qform(G, 0, w1r, w1r) + 2.f * qform(G, 1, w1r, w1r + 3)
           + 2.f * qform(G, 2, w1r, w1r + 6) + qform(G, 3, w1r + 3, w1r + 3)
           + 2.f * qform(G, 4, w1r + 3, w1r + 6) + qform(G, 5, w1r + 6, w1r + 6);
  m1 *= invN;
  float v1 = q1 * invN - m1 * m1;
  float sc1 = g1[f] * rsqrtf(v1 + EPS);
  float sh1 = be1[f] - m1 * sc1;

  float mc = 0.f;
#pragma unroll
  for (int r = 0; r < 3; r++)
#pragma unroll
    for (int j = 0; j < 3; j++) mc = fmaf(w2r[r * 3 + j], Sm[r * 3 + j], mc);
  float qc = qform(G, 0, w2r, w2r) + 2.f * qform(G, 1, w2r, w2r + 3)
           + 2.f * qform(G, 2, w2r, w2r + 6) + qform(G, 3, w2r + 3, w2r + 3)
           + 2.f * qform(G, 4, w2r + 3, w2r + 6) + qform(G, 5, w2r + 6, w2r + 6);
  const float* wA = w2r + 9;
  const float* wB = w2r + 12;
  float sc2o[3], sh2o[3];
#pragma unroll
  for (int k = 0; k < 3; k++) {
    const int a = 3 + 2 * k, b = 4 + 2 * k, p0 = 6 + 9 * k;
    float m2 = mc;
#pragma unroll
    for (int j = 0; j < 3; j++) {
      m2 = fmaf(wA[j], Sm[a * 3 + j], m2);
      m2 = fmaf(wB[j], Sm[b * 3 + j], m2);
    }
    float q2 = qc
      + 2.f * (qform(G, p0 + 0, w2r, wA) + qform(G, p0 + 1, w2r + 3, wA)
             + qform(G, p0 + 2, w2r + 6, wA) + qform(G, p0 + 3, w2r, wB)
             + qform(G, p0 + 4, w2r + 3, wB) + qform(G, p0 + 5, w2r + 6, wB))
      + qform(G, p0 + 6, wA, wA) + 2.f * qform(G, p0 + 7, wA, wB)
      + qform(G, p0 + 8, wB, wB);
    m2 *= invN;
    float v2 = q2 * invN - m2 * m2;
    float sck = g2[f] * rsqrtf(v2 + EPS);
    sc2o[k] = sck;
    sh2o[k] = be2[f] - m2 * sck;
  }

  _Float16* Aw = (_Float16*)(ws + AW_OFF);
  // conv1 row (M = 4f+0): weights*sc1, shift in k27
  {
    _Float16* rw = Aw + (size_t)(4 * f + 0) * 32;
#pragma unroll
    for (int k = 0; k < 32; k++) rw[k] = (_Float16)0.f;
#pragma unroll
    for (int idx = 0; idx < 9; idx++) rw[idx] = (_Float16)(w1r[idx] * sc1);
    rw[27] = (_Float16)sh1;
  }
  // conv2 rows (M = 4f+1+kk)
#pragma unroll
  for (int kk = 0; kk < 3; kk++) {
    _Float16* rw = Aw + (size_t)(4 * f + 1 + kk) * 32;
#pragma unroll
    for (int k = 0; k < 32; k++) rw[k] = (_Float16)0.f;
    const float sck = sc2o[kk];
#pragma unroll
    for (int idx = 0; idx < 9; idx++) rw[idx] = (_Float16)(w2r[idx] * sck);
    const int ra = 3 + 2 * kk, rb = 4 + 2 * kk;
#pragma unroll
    for (int j = 0; j < 3; j++) {
      rw[3 * ra + j] = (_Float16)(w2r[9 + j] * sck);
      rw[3 * rb + j] = (_Float16)(w2r[12 + j] * sck);
    }
    rw[27] = (_Float16)sh2o[kk];
  }
}

// ---------------- main: f16 MFMA over M=4f+conv, N=x, K=im2col taps ---------
__device__ __forceinline__ const float* rowptr(const int* __restrict__ xr, int r,
                                               const float* __restrict__ er,
                                               const float* __restrict__ ev) {
  if (r == 0) return ev + (size_t)xr[1] * EMB;
  if (r == 1) return er + (size_t)xr[0] * EMB;
  if (r == 2) return ev + (size_t)xr[3] * EMB;
  const int k = (r - 3) >> 1;
  return ((r - 3) & 1) ? ev + (size_t)xr[5 + 2 * k] * EMB
                       : er + (size_t)xr[4 + 2 * k] * EMB;
}

__global__ __launch_bounds__(256, 2) void main_mfma(
    const int* __restrict__ xb, const float* __restrict__ er,
    const float* __restrict__ ev, const float* __restrict__ fcw,
    const float* __restrict__ fcb, const float* __restrict__ ws,
    float* __restrict__ out) {
  __shared__ _Float16 Bm[SPBM][128][40];   // 40 KB; K-stride 40 halfs = 80 B
  const int tid = threadIdx.x;
  const int base = blockIdx.x * SPBM;

  // B build: im2col, f16. thread -> (sample, x)
  for (int job = tid; job < SPBM * 128; job += 256) {
    const int s = job >> 7, x = job & 127;
    const int* xr = xb + (size_t)(base + s) * 10;
    const int x1 = (x + 1 < 128) ? x + 1 : 127;   // clamp (cols >=126 masked by fcw)
    const int x2 = (x + 2 < 128) ? x + 2 : 127;
    _Float16* dst = &Bm[s][x][0];
#pragma unroll
    for (int r = 0; r < 9; r++) {
      const float* hp = rowptr(xr, r, er, ev);
      dst[3 * r + 0] = (_Float16)hp[x];
      dst[3 * r + 1] = (_Float16)hp[x1];
      dst[3 * r + 2] = (_Float16)hp[x2];
    }
    dst[27] = (_Float16)1.0f;                     // ones row -> bn shift via A
#pragma unroll
    for (int k = 28; k < 40; k++) dst[k] = (_Float16)0.0f;
  }
  __syncthreads();

  const int w = tid >> 6, l = tid & 63;           // wave <-> sample
  const int fl = l >> 4, xl = l & 15;
  const _Float16* __restrict__ Aw = (const _Float16*)(ws + AW_OFF);
  const float fcb0 = fcb[0];
  float psum = 0.f;

#pragma unroll 1
  for (int ntb = 0; ntb < 2; ++ntb) {
    half8 bf[4];
#pragma unroll
    for (int j = 0; j < 4; ++j)                   // B frag: col=l&15, k=(l>>4)*8..
      bf[j] = *(const half8*)&Bm[w][(ntb * 4 + j) * 16 + xl][fl * 8];
#pragma unroll 1
    for (int mtb = 0; mtb < 10; ++mtb) {
      half8 af[5];
#pragma unroll
      for (int i = 0; i < 5; ++i)                 // A frag: row=l&15, k=(l>>4)*8..
        af[i] = *(const half8*)&Aw[(size_t)((mtb * 5 + i) * 16 + xl) * 32 + fl * 8];
#pragma unroll
      for (int i = 0; i < 5; ++i) {
        const int f = (mtb * 5 + i) * 4 + fl;     // D row=(l>>4)*4+reg = 4f+conv
#pragma unroll
        for (int j = 0; j < 4; ++j) {
          f32x4v acc = __builtin_amdgcn_mfma_f32_16x16x32_f16(
              af[i], bf[j], (f32x4v){0.f, 0.f, 0.f, 0.f}, 0, 0, 0);
          const int x = (ntb * 4 + j) * 16 + xl;
          const float fcv = (x < W_OUT) ? fcw[f * W_OUT + x] : 0.f;
          float mv = fminf(fminf(acc[0], acc[1]), fminf(acc[2], acc[3]));
          psum = fmaf(fmaxf(mv, 0.f), fcv, psum); // min of relus = relu of min
        }
      }
    }
  }

#pragma unroll
  for (int off = 32; off; off >>= 1) psum += __shfl_xor(psum, off, 64);
  if (l == 0) out[base + w] = psum + fcb0;
}

extern "C" void kernel_launch(void* const* d_in, const int* in_sizes, int n_in,
                              void* d_out, int out_size, void* d_ws, size_t ws_size,
                              hipStream_t stream) {
  const int* xb    = (const int*)d_in[0];
  const float* er  = (const float*)d_in[3];
  const float* ev  = (const float*)d_in[4];
  const float* w1  = (const float*)d_in[5];
  const float* g1  = (const float*)d_in[7];
  const float* be1 = (const float*)d_in[8];
  const float* w2  = (const float*)d_in[9];
  const float* g2  = (const float*)d_in[11];
  const float* be2 = (const float*)d_in[12];
  const float* fcw = (const float*)d_in[13];
  const float* fcb = (const float*)d_in[14];
  float* ws  = (float*)d_ws;
  float* out = (float*)d_out;

  hipMemsetAsync(ws, 0, NSTAT * sizeof(float), stream);
  hipLaunchKernelGGL(stats_kernel, dim3(STATS_BLOCKS), dim3(256), 0, stream,
                     xb, er, ev, ws);
  hipLaunchKernelGGL(finalize_kernel, dim3(1), dim3(256), 0, stream,
                     w1, w2, g1, be1, g2, be2, ws);
  hipLaunchKernelGGL(main_mfma, dim3(MAIN_BLOCKS), dim3(256), 0, stream,
                     xb, er, ev, fcw, fcb, ws, out);
}